// Round 1
// baseline (3334.201 us; speedup 1.0000x reference)
//
#include <hip/hip_runtime.h>

#define LEAK 0.2f

constexpr int BB = 2;
constexpr int C  = 16;
constexpr int D  = 96, H = 96, W = 96;
constexpr int N  = D * H * W;          // 884736
constexpr int DS = 48;                 // dvf spatial
constexpr int C1 = 59;                 // 16 + 27 + 16

__device__ __forceinline__ float leaky(float v) { return v > 0.f ? v : LEAK * v; }

// ---------------------------------------------------------------------------
// Kernel 1: fused dvf trilinear upsample (align_corners) + warp of source.
// One thread per (b, z, y, x) output voxel; writes all 16 channels.
// ---------------------------------------------------------------------------
__global__ void warp_kernel(const float* __restrict__ src, const float* __restrict__ dvf,
                            float* __restrict__ warped, int total) {
    int i = blockIdx.x * blockDim.x + threadIdx.x;
    if (i >= total) return;
    int b = i / N; int r = i - b * N;
    int z = r / (H * W); int rem = r - z * (H * W); int y = rem / W; int x = rem - y * W;

    // upsample coords: pos = idx * (48-1)/(96-1)
    const float sc = 47.0f / 95.0f;
    float pz = z * sc, py = y * sc, px = x * sc;
    int z0 = (int)pz, y0 = (int)py, x0 = (int)px;          // pos >= 0
    int z1 = min(z0 + 1, DS - 1), y1 = min(y0 + 1, DS - 1), x1 = min(x0 + 1, DS - 1);
    float wz = pz - z0, wy = py - y0, wx = px - x0;

    const float* dv = dvf + (size_t)b * 3 * DS * DS * DS;
    float fl[3];
#pragma unroll
    for (int c = 0; c < 3; ++c) {
        const float* p = dv + (size_t)c * DS * DS * DS;
        float c000 = p[(z0 * DS + y0) * DS + x0], c001 = p[(z0 * DS + y0) * DS + x1];
        float c010 = p[(z0 * DS + y1) * DS + x0], c011 = p[(z0 * DS + y1) * DS + x1];
        float c100 = p[(z1 * DS + y0) * DS + x0], c101 = p[(z1 * DS + y0) * DS + x1];
        float c110 = p[(z1 * DS + y1) * DS + x0], c111 = p[(z1 * DS + y1) * DS + x1];
        float a00 = c000 * (1.f - wx) + c001 * wx;
        float a01 = c010 * (1.f - wx) + c011 * wx;
        float a10 = c100 * (1.f - wx) + c101 * wx;
        float a11 = c110 * (1.f - wx) + c111 * wx;
        float b0_ = a00 * (1.f - wy) + a01 * wy;
        float b1_ = a10 * (1.f - wy) + a11 * wy;
        fl[c] = b0_ * (1.f - wz) + b1_ * wz;
    }

    // warp sample coords
    float zz = z + fl[0], yy = y + fl[1], xx = x + fl[2];
    float zf = floorf(zz), yf = floorf(yy), xf = floorf(xx);
    float fz = zz - zf, fy = yy - yf, fx = xx - xf;
    int iz0 = (int)zf, iy0 = (int)yf, ix0 = (int)xf;
    int iz1 = iz0 + 1, iy1 = iy0 + 1, ix1 = ix0 + 1;

    float vz0 = ((unsigned)iz0 < (unsigned)D) ? 1.f : 0.f;
    float vy0 = ((unsigned)iy0 < (unsigned)H) ? 1.f : 0.f;
    float vx0 = ((unsigned)ix0 < (unsigned)W) ? 1.f : 0.f;
    float vz1 = ((unsigned)iz1 < (unsigned)D) ? 1.f : 0.f;
    float vy1 = ((unsigned)iy1 < (unsigned)H) ? 1.f : 0.f;
    float vx1 = ((unsigned)ix1 < (unsigned)W) ? 1.f : 0.f;

    int cz0 = min(max(iz0, 0), D - 1), cy0 = min(max(iy0, 0), H - 1), cx0 = min(max(ix0, 0), W - 1);
    int cz1 = min(max(iz1, 0), D - 1), cy1 = min(max(iy1, 0), H - 1), cx1 = min(max(ix1, 0), W - 1);

    float w000 = (1.f - fz) * (1.f - fy) * (1.f - fx) * vz0 * vy0 * vx0;
    float w001 = (1.f - fz) * (1.f - fy) * fx         * vz0 * vy0 * vx1;
    float w010 = (1.f - fz) * fy * (1.f - fx)         * vz0 * vy1 * vx0;
    float w011 = (1.f - fz) * fy * fx                 * vz0 * vy1 * vx1;
    float w100 = fz * (1.f - fy) * (1.f - fx)         * vz1 * vy0 * vx0;
    float w101 = fz * (1.f - fy) * fx                 * vz1 * vy0 * vx1;
    float w110 = fz * fy * (1.f - fx)                 * vz1 * vy1 * vx0;
    float w111 = fz * fy * fx                         * vz1 * vy1 * vx1;

    int o000 = (cz0 * H + cy0) * W + cx0, o001 = (cz0 * H + cy0) * W + cx1;
    int o010 = (cz0 * H + cy1) * W + cx0, o011 = (cz0 * H + cy1) * W + cx1;
    int o100 = (cz1 * H + cy0) * W + cx0, o101 = (cz1 * H + cy0) * W + cx1;
    int o110 = (cz1 * H + cy1) * W + cx0, o111 = (cz1 * H + cy1) * W + cx1;

    const float* sb = src + (size_t)b * C * N;
    float* wb = warped + (size_t)b * C * N + r;
#pragma unroll 4
    for (int c = 0; c < C; ++c) {
        const float* p = sb + (size_t)c * N;
        float v = p[o000] * w000 + p[o001] * w001 + p[o010] * w010 + p[o011] * w011
                + p[o100] * w100 + p[o101] * w101 + p[o110] * w110 + p[o111] * w111;
        wb[(size_t)c * N] = v;
    }
}

// ---------------------------------------------------------------------------
// Kernel 2: 27-shift cost volume, channel-mean, leaky. Zeros padding handled
// by clamped offsets + end mask (invalid shift => whole term zero).
// ---------------------------------------------------------------------------
__global__ void corr_kernel(const float* __restrict__ tgt, const float* __restrict__ warped,
                            float* __restrict__ feat, int total) {
    int i = blockIdx.x * blockDim.x + threadIdx.x;
    if (i >= total) return;
    int b = i / N; int r = i - b * N;
    int z = r / (H * W); int rem = r - z * (H * W); int y = rem / W; int x = rem - y * W;

    int offs[27]; float msk[27];
#pragma unroll
    for (int k = 0; k < 27; ++k) {
        int dz = k / 9 - 1, dy = (k / 3) % 3 - 1, dx = k % 3 - 1;
        int zc = z + dz, yc = y + dy, xc = x + dx;
        bool v = ((unsigned)zc < (unsigned)D) && ((unsigned)yc < (unsigned)H) && ((unsigned)xc < (unsigned)W);
        int zk = min(max(zc, 0), D - 1), yk = min(max(yc, 0), H - 1), xk = min(max(xc, 0), W - 1);
        offs[k] = (zk * H + yk) * W + xk;
        msk[k] = v ? 1.f : 0.f;
    }

    float acc[27];
#pragma unroll
    for (int k = 0; k < 27; ++k) acc[k] = 0.f;

    const float* tb = tgt + (size_t)b * C * N + r;
    const float* wb = warped + (size_t)b * C * N;
    for (int c = 0; c < C; ++c) {
        float t = tb[(size_t)c * N];
        const float* p = wb + (size_t)c * N;
#pragma unroll
        for (int k = 0; k < 27; ++k) acc[k] += t * p[offs[k]];
    }

    float* fo = feat + (size_t)b * 27 * N + r;
#pragma unroll
    for (int k = 0; k < 27; ++k) {
        float v = acc[k] * (1.f / 16.f) * msk[k];
        fo[(size_t)k * N] = leaky(v);
    }
}

// ---------------------------------------------------------------------------
// Kernel 3: conv1 over concat(source, feat27, target) -> 16 ch, bias+leaky.
// Tap-outer loop; per-tap weight slice [59][16] staged in LDS (broadcast read).
// ---------------------------------------------------------------------------
__global__ void conv1_kernel(const float* __restrict__ src, const float* __restrict__ feat,
                             const float* __restrict__ tgt, const float* __restrict__ w1,
                             const float* __restrict__ b1, float* __restrict__ fo, int total) {
    __shared__ float wsl[C1 * 16];
    int i = blockIdx.x * blockDim.x + threadIdx.x;
    bool active = i < total;
    int b = 0, r = 0, z = 0, y = 0, x = 0;
    if (active) {
        b = i / N; r = i - b * N;
        z = r / (H * W); int rem = r - z * (H * W); y = rem / W; x = rem - y * W;
    }
    float acc[16];
#pragma unroll
    for (int co = 0; co < 16; ++co) acc[co] = 0.f;

    const float* sb = src + (size_t)b * C * N;
    const float* fb = feat + (size_t)b * 27 * N;
    const float* gb = tgt + (size_t)b * C * N;

    for (int k = 0; k < 27; ++k) {
        __syncthreads();   // protect previous iteration's readers
        for (int j = threadIdx.x; j < C1 * 16; j += blockDim.x) {
            int ci = j >> 4; int co = j & 15;
            wsl[j] = w1[((size_t)co * C1 + ci) * 27 + k];
        }
        __syncthreads();

        int dz = k / 9 - 1, dy = (k / 3) % 3 - 1, dx = k % 3 - 1;
        int zc = z + dz, yc = y + dy, xc = x + dx;
        if (active && (unsigned)zc < (unsigned)D && (unsigned)yc < (unsigned)H && (unsigned)xc < (unsigned)W) {
            int o = (zc * H + yc) * W + xc;
#pragma unroll 4
            for (int ci = 0; ci < 16; ++ci) {
                float v = sb[(size_t)ci * N + o];
                const float* wp = &wsl[ci * 16];
#pragma unroll
                for (int co = 0; co < 16; ++co) acc[co] += wp[co] * v;
            }
#pragma unroll 3
            for (int ci = 0; ci < 27; ++ci) {
                float v = fb[(size_t)ci * N + o];
                const float* wp = &wsl[(16 + ci) * 16];
#pragma unroll
                for (int co = 0; co < 16; ++co) acc[co] += wp[co] * v;
            }
#pragma unroll 4
            for (int ci = 0; ci < 16; ++ci) {
                float v = gb[(size_t)ci * N + o];
                const float* wp = &wsl[(43 + ci) * 16];
#pragma unroll
                for (int co = 0; co < 16; ++co) acc[co] += wp[co] * v;
            }
        }
    }

    if (active) {
        float* op = fo + (size_t)b * C * N + r;
#pragma unroll
        for (int co = 0; co < 16; ++co) op[(size_t)co * N] = leaky(acc[co] + b1[co]);
    }
}

// ---------------------------------------------------------------------------
// Kernel 4: conv2 (16->16) + bias + leaky + residual add of input.
// Full weight tensor (27*16*16 = 27.6 KB) staged once in LDS.
// ---------------------------------------------------------------------------
__global__ void conv2_kernel(const float* __restrict__ fin, const float* __restrict__ w2,
                             const float* __restrict__ b2, float* __restrict__ fo, int total) {
    __shared__ float wsl[27 * 16 * 16];
    for (int j = threadIdx.x; j < 27 * 16 * 16; j += blockDim.x) {
        int k = j >> 8; int rr = j & 255; int ci = rr >> 4; int co = rr & 15;
        wsl[j] = w2[((size_t)co * 16 + ci) * 27 + k];
    }
    __syncthreads();

    int i = blockIdx.x * blockDim.x + threadIdx.x;
    if (i >= total) return;
    int b = i / N; int r = i - b * N;
    int z = r / (H * W); int rem = r - z * (H * W); int y = rem / W; int x = rem - y * W;

    float acc[16];
#pragma unroll
    for (int co = 0; co < 16; ++co) acc[co] = 0.f;

    const float* ib = fin + (size_t)b * C * N;
    for (int k = 0; k < 27; ++k) {
        int dz = k / 9 - 1, dy = (k / 3) % 3 - 1, dx = k % 3 - 1;
        int zc = z + dz, yc = y + dy, xc = x + dx;
        if ((unsigned)zc < (unsigned)D && (unsigned)yc < (unsigned)H && (unsigned)xc < (unsigned)W) {
            int o = (zc * H + yc) * W + xc;
            const float* wk = &wsl[k * 256];
#pragma unroll 4
            for (int ci = 0; ci < 16; ++ci) {
                float v = ib[(size_t)ci * N + o];
                const float* wp = &wk[ci * 16];
#pragma unroll
                for (int co = 0; co < 16; ++co) acc[co] += wp[co] * v;
            }
        }
    }

    float* op = fo + (size_t)b * C * N + r;
#pragma unroll
    for (int co = 0; co < 16; ++co) {
        float res = ib[(size_t)co * N + r];
        op[(size_t)co * N] = res + leaky(acc[co] + b2[co]);
    }
}

// ---------------------------------------------------------------------------
// Kernel 5: conv3 (16->3) + bias + leaky -> output.
// ---------------------------------------------------------------------------
__global__ void conv3_kernel(const float* __restrict__ fin, const float* __restrict__ w3,
                             const float* __restrict__ b3, float* __restrict__ out, int total) {
    __shared__ float wsl[27 * 16 * 3];
    for (int j = threadIdx.x; j < 27 * 16 * 3; j += blockDim.x) {
        int k = j / 48; int rr = j - k * 48; int ci = rr / 3; int co = rr - ci * 3;
        wsl[j] = w3[((size_t)co * 16 + ci) * 27 + k];
    }
    __syncthreads();

    int i = blockIdx.x * blockDim.x + threadIdx.x;
    if (i >= total) return;
    int b = i / N; int r = i - b * N;
    int z = r / (H * W); int rem = r - z * (H * W); int y = rem / W; int x = rem - y * W;

    float acc[3] = {0.f, 0.f, 0.f};
    const float* ib = fin + (size_t)b * C * N;
    for (int k = 0; k < 27; ++k) {
        int dz = k / 9 - 1, dy = (k / 3) % 3 - 1, dx = k % 3 - 1;
        int zc = z + dz, yc = y + dy, xc = x + dx;
        if ((unsigned)zc < (unsigned)D && (unsigned)yc < (unsigned)H && (unsigned)xc < (unsigned)W) {
            int o = (zc * H + yc) * W + xc;
            const float* wk = &wsl[k * 48];
#pragma unroll 4
            for (int ci = 0; ci < 16; ++ci) {
                float v = ib[(size_t)ci * N + o];
                acc[0] += wk[ci * 3 + 0] * v;
                acc[1] += wk[ci * 3 + 1] * v;
                acc[2] += wk[ci * 3 + 2] * v;
            }
        }
    }

    float* op = out + (size_t)b * 3 * N + r;
#pragma unroll
    for (int co = 0; co < 3; ++co) op[(size_t)co * N] = leaky(acc[co] + b3[co]);
}

// ---------------------------------------------------------------------------
extern "C" void kernel_launch(void* const* d_in, const int* in_sizes, int n_in,
                              void* d_out, int out_size, void* d_ws, size_t ws_size,
                              hipStream_t stream) {
    const float* source = (const float*)d_in[0];
    const float* target = (const float*)d_in[1];
    const float* dvf    = (const float*)d_in[2];
    const float* w1 = (const float*)d_in[3];
    const float* b1 = (const float*)d_in[4];
    const float* w2 = (const float*)d_in[5];
    const float* b2 = (const float*)d_in[6];
    const float* w3 = (const float*)d_in[7];
    const float* b3 = (const float*)d_in[8];
    float* out = (float*)d_out;
    float* ws  = (float*)d_ws;

    // per-batch float counts: warped/f (reused as f2) + feat27 + f
    size_t perBatch = (size_t)2 * C * N + (size_t)27 * N;
    int chunk = (ws_size >= perBatch * BB * sizeof(float)) ? BB : 1;

    for (int b0 = 0; b0 < BB; b0 += chunk) {
        int nb = (b0 + chunk <= BB) ? chunk : (BB - b0);
        size_t nW = (size_t)nb * C * N;
        size_t nF = (size_t)nb * 27 * N;
        float* warped = ws;
        float* feat   = ws + nW;
        float* f      = ws + nW + nF;
        float* f2     = warped;   // warped dead after corr

        const float* sp = source + (size_t)b0 * C * N;
        const float* tp = target + (size_t)b0 * C * N;
        const float* dp = dvf + (size_t)b0 * 3 * DS * DS * DS;
        float* op = out + (size_t)b0 * 3 * N;

        int total = nb * N;
        int blocks = (total + 255) / 256;
        warp_kernel<<<blocks, 256, 0, stream>>>(sp, dp, warped, total);
        corr_kernel<<<blocks, 256, 0, stream>>>(tp, warped, feat, total);
        conv1_kernel<<<blocks, 256, 0, stream>>>(sp, feat, tp, w1, b1, f, total);
        conv2_kernel<<<blocks, 256, 0, stream>>>(f, w2, b2, f2, total);
        conv3_kernel<<<blocks, 256, 0, stream>>>(f2, w3, b3, op, total);
    }
}

// Round 3
// 2721.559 us; speedup vs baseline: 1.2251x; 1.2251x over previous
//
#include <hip/hip_runtime.h>

#define LEAK 0.2f

constexpr int BB = 2;
constexpr int C  = 16;
constexpr int D  = 96, H = 96, W = 96;
constexpr int N  = D * H * W;          // 884736
constexpr int HW = H * W;              // 9216
constexpr int DS = 48;                 // dvf spatial

constexpr int CP1  = 64;               // conv1 input channels padded 59->64
constexpr int NKB1 = (27 * CP1) / 32;  // 54 K-blocks for conv1
constexpr int NKB2 = (28 * 16) / 32;   // 14 K-blocks for conv2/conv3 (tap 27 zero-pad)

typedef unsigned short ushort_t;
typedef __attribute__((ext_vector_type(8))) short  short8;
typedef __attribute__((ext_vector_type(8))) unsigned short ushort8;
typedef __attribute__((ext_vector_type(4))) unsigned short ushort4v;
typedef __attribute__((ext_vector_type(4))) float  floatx4;

__device__ __forceinline__ float leaky(float v) { return v > 0.f ? v : LEAK * v; }

__device__ __forceinline__ ushort_t f2bf(float f) {
    union { float f; unsigned u; } v; v.f = f;
    unsigned r = v.u + 0x7FFF + ((v.u >> 16) & 1);
    return (ushort_t)(r >> 16);
}
__device__ __forceinline__ float bf2f(ushort_t h) {
    union { unsigned u; float f; } v; v.u = ((unsigned)h) << 16;
    return v.f;
}

// ---------------------------------------------------------------------------
// Weight repack into MFMA A-fragment order (bf16).
// Wf[kb][lane][e] = W[m = lane&15][k = kb*32 + (lane>>4)*8 + e]
// conv1: k -> tap = k>>6, ci = k&63 (ci>=59 zero)
// conv2/3: k -> tap = k>>4, ci = k&15 (tap>=27 zero; conv3 m>=3 zero)
// ---------------------------------------------------------------------------
__global__ void wprep_kernel(const float* __restrict__ w1, const float* __restrict__ w2,
                             const float* __restrict__ w3,
                             ushort_t* __restrict__ W1f, ushort_t* __restrict__ W2f,
                             ushort_t* __restrict__ W3f) {
    int i = blockIdx.x * blockDim.x + threadIdx.x;
    if (i < NKB1 * 512) {
        int kb = i >> 9, rem = i & 511;
        int lane = rem >> 3, e = rem & 7;
        int m = lane & 15;
        int k = kb * 32 + ((lane >> 4) << 3) + e;
        int tap = k >> 6, ci = k & 63;
        float v = (ci < 59) ? w1[((size_t)m * 59 + ci) * 27 + tap] : 0.f;
        W1f[i] = f2bf(v);
        return;
    }
    i -= NKB1 * 512;
    if (i < NKB2 * 512) {
        int kb = i >> 9, rem = i & 511;
        int lane = rem >> 3, e = rem & 7;
        int m = lane & 15;
        int k = kb * 32 + ((lane >> 4) << 3) + e;
        int tap = k >> 4, ci = k & 15;
        float v = (tap < 27) ? w2[((size_t)m * 16 + ci) * 27 + tap] : 0.f;
        W2f[i] = f2bf(v);
        return;
    }
    i -= NKB2 * 512;
    if (i < NKB2 * 512) {
        int kb = i >> 9, rem = i & 511;
        int lane = rem >> 3, e = rem & 7;
        int m = lane & 15;
        int k = kb * 32 + ((lane >> 4) << 3) + e;
        int tap = k >> 4, ci = k & 15;
        float v = (tap < 27 && m < 3) ? w3[((size_t)m * 16 + ci) * 27 + tap] : 0.f;
        W3f[i] = f2bf(v);
    }
}

// ---------------------------------------------------------------------------
// Kernel 1: fused dvf trilinear upsample (align_corners) + warp of source.
// Writes planar fp32 `warped` (consumed by corr_pack).
// ---------------------------------------------------------------------------
__global__ void warp_kernel(const float* __restrict__ src, const float* __restrict__ dvf,
                            float* __restrict__ warped, int total) {
    int i = blockIdx.x * blockDim.x + threadIdx.x;
    if (i >= total) return;
    int b = i / N; int r = i - b * N;
    int z = r / HW; int rem = r - z * HW; int y = rem / W; int x = rem - y * W;

    const float sc = 47.0f / 95.0f;
    float pz = z * sc, py = y * sc, px = x * sc;
    int z0 = (int)pz, y0 = (int)py, x0 = (int)px;
    int z1 = min(z0 + 1, DS - 1), y1 = min(y0 + 1, DS - 1), x1 = min(x0 + 1, DS - 1);
    float wz = pz - z0, wy = py - y0, wx = px - x0;

    const float* dv = dvf + (size_t)b * 3 * DS * DS * DS;
    float fl[3];
#pragma unroll
    for (int c = 0; c < 3; ++c) {
        const float* p = dv + (size_t)c * DS * DS * DS;
        float c000 = p[(z0 * DS + y0) * DS + x0], c001 = p[(z0 * DS + y0) * DS + x1];
        float c010 = p[(z0 * DS + y1) * DS + x0], c011 = p[(z0 * DS + y1) * DS + x1];
        float c100 = p[(z1 * DS + y0) * DS + x0], c101 = p[(z1 * DS + y0) * DS + x1];
        float c110 = p[(z1 * DS + y1) * DS + x0], c111 = p[(z1 * DS + y1) * DS + x1];
        float a00 = c000 * (1.f - wx) + c001 * wx;
        float a01 = c010 * (1.f - wx) + c011 * wx;
        float a10 = c100 * (1.f - wx) + c101 * wx;
        float a11 = c110 * (1.f - wx) + c111 * wx;
        float b0_ = a00 * (1.f - wy) + a01 * wy;
        float b1_ = a10 * (1.f - wy) + a11 * wy;
        fl[c] = b0_ * (1.f - wz) + b1_ * wz;
    }

    float zz = z + fl[0], yy = y + fl[1], xx = x + fl[2];
    float zf = floorf(zz), yf = floorf(yy), xf = floorf(xx);
    float fz = zz - zf, fy = yy - yf, fx = xx - xf;
    int iz0 = (int)zf, iy0 = (int)yf, ix0 = (int)xf;
    int iz1 = iz0 + 1, iy1 = iy0 + 1, ix1 = ix0 + 1;

    float vz0 = ((unsigned)iz0 < (unsigned)D) ? 1.f : 0.f;
    float vy0 = ((unsigned)iy0 < (unsigned)H) ? 1.f : 0.f;
    float vx0 = ((unsigned)ix0 < (unsigned)W) ? 1.f : 0.f;
    float vz1 = ((unsigned)iz1 < (unsigned)D) ? 1.f : 0.f;
    float vy1 = ((unsigned)iy1 < (unsigned)H) ? 1.f : 0.f;
    float vx1 = ((unsigned)ix1 < (unsigned)W) ? 1.f : 0.f;

    int cz0 = min(max(iz0, 0), D - 1), cy0 = min(max(iy0, 0), H - 1), cx0 = min(max(ix0, 0), W - 1);
    int cz1 = min(max(iz1, 0), D - 1), cy1 = min(max(iy1, 0), H - 1), cx1 = min(max(ix1, 0), W - 1);

    float w000 = (1.f - fz) * (1.f - fy) * (1.f - fx) * vz0 * vy0 * vx0;
    float w001 = (1.f - fz) * (1.f - fy) * fx         * vz0 * vy0 * vx1;
    float w010 = (1.f - fz) * fy * (1.f - fx)         * vz0 * vy1 * vx0;
    float w011 = (1.f - fz) * fy * fx                 * vz0 * vy1 * vx1;
    float w100 = fz * (1.f - fy) * (1.f - fx)         * vz1 * vy0 * vx0;
    float w101 = fz * (1.f - fy) * fx                 * vz1 * vy0 * vx1;
    float w110 = fz * fy * (1.f - fx)                 * vz1 * vy1 * vx0;
    float w111 = fz * fy * fx                         * vz1 * vy1 * vx1;

    int o000 = (cz0 * H + cy0) * W + cx0, o001 = (cz0 * H + cy0) * W + cx1;
    int o010 = (cz0 * H + cy1) * W + cx0, o011 = (cz0 * H + cy1) * W + cx1;
    int o100 = (cz1 * H + cy0) * W + cx0, o101 = (cz1 * H + cy0) * W + cx1;
    int o110 = (cz1 * H + cy1) * W + cx0, o111 = (cz1 * H + cy1) * W + cx1;

    const float* sb = src + (size_t)b * C * N;
    float* wb = warped + (size_t)b * C * N + r;
#pragma unroll 4
    for (int c = 0; c < C; ++c) {
        const float* p = sb + (size_t)c * N;
        float v = p[o000] * w000 + p[o001] * w001 + p[o010] * w010 + p[o011] * w011
                + p[o100] * w100 + p[o101] * w101 + p[o110] * w110 + p[o111] * w111;
        wb[(size_t)c * N] = v;
    }
}

// ---------------------------------------------------------------------------
// Kernel 2: corr (27-shift cost volume, channel-mean, leaky) + pack:
// writes full NHWC bf16 row X1[v][64] = [src 0..15 | feat 16..42 | tgt 43..58 | 0 pad]
// ---------------------------------------------------------------------------
__global__ void corr_pack_kernel(const float* __restrict__ src, const float* __restrict__ tgt,
                                 const float* __restrict__ warped, ushort_t* __restrict__ X1,
                                 int total) {
    int nwg = gridDim.x;
    int lb = (blockIdx.x & 7) * (nwg >> 3) + (blockIdx.x >> 3);   // XCD-chunked swizzle
    int i = lb * blockDim.x + threadIdx.x;
    if (i >= total) return;
    int b = i / N; int r = i - b * N;
    int z = r / HW; int rem = r - z * HW; int y = rem / W; int x = rem - y * W;

    int offs[27]; float msk[27];
#pragma unroll
    for (int k = 0; k < 27; ++k) {
        int dz = k / 9 - 1, dy = (k / 3) % 3 - 1, dx = k % 3 - 1;
        int zc = z + dz, yc = y + dy, xc = x + dx;
        bool v = ((unsigned)zc < (unsigned)D) && ((unsigned)yc < (unsigned)H) && ((unsigned)xc < (unsigned)W);
        int zk = min(max(zc, 0), D - 1), yk = min(max(yc, 0), H - 1), xk = min(max(xc, 0), W - 1);
        offs[k] = (zk * H + yk) * W + xk;
        msk[k] = v ? 1.f : 0.f;
    }

    float tv[16], sv[16];
#pragma unroll 4
    for (int c = 0; c < C; ++c) tv[c] = tgt[((size_t)b * C + c) * N + r];
#pragma unroll 4
    for (int c = 0; c < C; ++c) sv[c] = src[((size_t)b * C + c) * N + r];

    float acc[27];
#pragma unroll
    for (int k = 0; k < 27; ++k) acc[k] = 0.f;

    const float* wb = warped + (size_t)b * C * N;
    for (int c = 0; c < C; ++c) {
        float t = tv[c];
        const float* p = wb + (size_t)c * N;
#pragma unroll
        for (int k = 0; k < 27; ++k) acc[k] += t * p[offs[k]];
    }

    ushort8 rowv[8];
#pragma unroll
    for (int c = 0; c < 16; ++c) rowv[c >> 3][c & 7] = f2bf(sv[c]);
#pragma unroll
    for (int k = 0; k < 27; ++k) {
        int p = 16 + k;
        rowv[p >> 3][p & 7] = f2bf(leaky(acc[k] * (1.f / 16.f) * msk[k]));
    }
#pragma unroll
    for (int c = 0; c < 16; ++c) { int p = 43 + c; rowv[p >> 3][p & 7] = f2bf(tv[c]); }
#pragma unroll
    for (int p = 59; p < 64; ++p) rowv[p >> 3][p & 7] = 0;

    ushort8* dst = (ushort8*)(X1 + ((size_t)b * N + r) * CP1);
#pragma unroll
    for (int j = 0; j < 8; ++j) dst[j] = rowv[j];
}

// ---------------------------------------------------------------------------
// Kernel 3: conv1 via MFMA implicit GEMM. 4 waves/block, each wave: 16 Cout x
// 64 voxels (4 accumulators). B-frag = 16B row-slice of X1 at tap-shifted voxel.
// Writes f as NHWC bf16 X2[v][16].
// ---------------------------------------------------------------------------
__global__ __launch_bounds__(256) void conv1_mfma(const ushort_t* __restrict__ X1,
                                                  const ushort_t* __restrict__ W1f,
                                                  const float* __restrict__ b1,
                                                  ushort_t* __restrict__ X2) {
    int nwg = gridDim.x;
    int lb = (blockIdx.x & 7) * (nwg >> 3) + (blockIdx.x >> 3);
    int b = lb / (N / 256);
    int vbase = (lb - b * (N / 256)) * 256;
    int w = threadIdx.x >> 6, l = threadIdx.x & 63;
    int ln15 = l & 15, lhi = l >> 4;

    const ushort_t* Xb = X1 + (size_t)b * N * CP1;

    int vg[4], zg[4], yg[4], xg[4];
#pragma unroll
    for (int g = 0; g < 4; ++g) {
        int v = vbase + w * 64 + g * 16;
        vg[g] = v;
        zg[g] = v / HW; int rem = v - zg[g] * HW; yg[g] = rem / W; xg[g] = rem - yg[g] * W;
    }
    floatx4 acc[4] = {};
    int cib = lhi << 3;

    for (int kb = 0; kb < NKB1; ++kb) {
        short8 a = *(const short8*)(W1f + ((size_t)(kb * 64 + l)) * 8);
        int tap = kb >> 1, half = kb & 1;
        int dz = tap / 9 - 1, dy = (tap / 3) % 3 - 1, dx = tap % 3 - 1;
        int doff = (dz * H + dy) * W + dx;
        int cb = half * 32 + cib;
#pragma unroll
        for (int g = 0; g < 4; ++g) {
            bool vzy = ((unsigned)(zg[g] + dz) < (unsigned)D) & ((unsigned)(yg[g] + dy) < (unsigned)H);
            int xl = xg[g] + ln15 + dx;
            bool ok = vzy & ((unsigned)xl < (unsigned)W);
            int vv = ok ? (vg[g] + ln15 + doff) : (vg[g] + ln15);
            short8 bf = *(const short8*)(Xb + (size_t)vv * CP1 + cb);
            short8 zf = {};
            bf = ok ? bf : zf;
            acc[g] = __builtin_amdgcn_mfma_f32_16x16x32_bf16(a, bf, acc[g], 0, 0, 0);
        }
    }

    int co0 = lhi << 2;
    float bias[4] = {b1[co0], b1[co0 + 1], b1[co0 + 2], b1[co0 + 3]};
#pragma unroll
    for (int g = 0; g < 4; ++g) {
        int v = vg[g] + ln15;
        ushort4v o;
#pragma unroll
        for (int j = 0; j < 4; ++j) o[j] = f2bf(leaky(acc[g][j] + bias[j]));
        *(ushort4v*)(X2 + ((size_t)b * N + v) * 16 + co0) = o;
    }
}

// ---------------------------------------------------------------------------
// Kernel 4: conv2 via MFMA + residual. X2 -> X3 (NHWC bf16). K = 28 taps x 16 ch.
// ---------------------------------------------------------------------------
__global__ __launch_bounds__(256) void conv2_mfma(const ushort_t* __restrict__ X2,
                                                  const ushort_t* __restrict__ W2f,
                                                  const float* __restrict__ b2,
                                                  ushort_t* __restrict__ X3) {
    int nwg = gridDim.x;
    int lb = (blockIdx.x & 7) * (nwg >> 3) + (blockIdx.x >> 3);
    int b = lb / (N / 256);
    int vbase = (lb - b * (N / 256)) * 256;
    int w = threadIdx.x >> 6, l = threadIdx.x & 63;
    int ln15 = l & 15, lhi = l >> 4;

    const ushort_t* Xb = X2 + (size_t)b * N * 16;

    int vg[4], zg[4], yg[4], xg[4];
#pragma unroll
    for (int g = 0; g < 4; ++g) {
        int v = vbase + w * 64 + g * 16;
        vg[g] = v;
        zg[g] = v / HW; int rem = v - zg[g] * HW; yg[g] = rem / W; xg[g] = rem - yg[g] * W;
    }
    floatx4 acc[4] = {};
    int cb = (lhi & 1) << 3;

    for (int kb = 0; kb < NKB2; ++kb) {
        short8 a = *(const short8*)(W2f + ((size_t)(kb * 64 + l)) * 8);
        int t = kb * 2 + (lhi >> 1);
        int tt = (t < 27) ? t : 13;                 // pad tap -> center (always valid)
        int dz = tt / 9 - 1, dy = (tt / 3) % 3 - 1, dx = tt % 3 - 1;
        int doff = (dz * H + dy) * W + dx;
#pragma unroll
        for (int g = 0; g < 4; ++g) {
            bool vzy = ((unsigned)(zg[g] + dz) < (unsigned)D) & ((unsigned)(yg[g] + dy) < (unsigned)H);
            int xl = xg[g] + ln15 + dx;
            bool ok = vzy & ((unsigned)xl < (unsigned)W);
            int vv = ok ? (vg[g] + ln15 + doff) : (vg[g] + ln15);
            short8 bf = *(const short8*)(Xb + (size_t)vv * 16 + cb);
            short8 zf = {};
            bf = ok ? bf : zf;
            acc[g] = __builtin_amdgcn_mfma_f32_16x16x32_bf16(a, bf, acc[g], 0, 0, 0);
        }
    }

    int co0 = lhi << 2;
    float bias[4] = {b2[co0], b2[co0 + 1], b2[co0 + 2], b2[co0 + 3]};
#pragma unroll
    for (int g = 0; g < 4; ++g) {
        int v = vg[g] + ln15;
        ushort4v res = *(const ushort4v*)(Xb + (size_t)v * 16 + co0);
        ushort4v o;
#pragma unroll
        for (int j = 0; j < 4; ++j)
            o[j] = f2bf(bf2f(res[j]) + leaky(acc[g][j] + bias[j]));
        *(ushort4v*)(X3 + ((size_t)b * N + v) * 16 + co0) = o;
    }
}

// ---------------------------------------------------------------------------
// Kernel 5: conv3 via MFMA (3 valid output rows). X3 -> fp32 planar out.
// ---------------------------------------------------------------------------
__global__ __launch_bounds__(256) void conv3_mfma(const ushort_t* __restrict__ X3,
                                                  const ushort_t* __restrict__ W3f,
                                                  const float* __restrict__ b3,
                                                  float* __restrict__ out) {
    int nwg = gridDim.x;
    int lb = (blockIdx.x & 7) * (nwg >> 3) + (blockIdx.x >> 3);
    int b = lb / (N / 256);
    int vbase = (lb - b * (N / 256)) * 256;
    int w = threadIdx.x >> 6, l = threadIdx.x & 63;
    int ln15 = l & 15, lhi = l >> 4;

    const ushort_t* Xb = X3 + (size_t)b * N * 16;

    int vg[4], zg[4], yg[4], xg[4];
#pragma unroll
    for (int g = 0; g < 4; ++g) {
        int v = vbase + w * 64 + g * 16;
        vg[g] = v;
        zg[g] = v / HW; int rem = v - zg[g] * HW; yg[g] = rem / W; xg[g] = rem - yg[g] * W;
    }
    floatx4 acc[4] = {};
    int cb = (lhi & 1) << 3;

    for (int kb = 0; kb < NKB2; ++kb) {
        short8 a = *(const short8*)(W3f + ((size_t)(kb * 64 + l)) * 8);
        int t = kb * 2 + (lhi >> 1);
        int tt = (t < 27) ? t : 13;
        int dz = tt / 9 - 1, dy = (tt / 3) % 3 - 1, dx = tt % 3 - 1;
        int doff = (dz * H + dy) * W + dx;
#pragma unroll
        for (int g = 0; g < 4; ++g) {
            bool vzy = ((unsigned)(zg[g] + dz) < (unsigned)D) & ((unsigned)(yg[g] + dy) < (unsigned)H);
            int xl = xg[g] + ln15 + dx;
            bool ok = vzy & ((unsigned)xl < (unsigned)W);
            int vv = ok ? (vg[g] + ln15 + doff) : (vg[g] + ln15);
            short8 bf = *(const short8*)(Xb + (size_t)vv * 16 + cb);
            short8 zf = {};
            bf = ok ? bf : zf;
            acc[g] = __builtin_amdgcn_mfma_f32_16x16x32_bf16(a, bf, acc[g], 0, 0, 0);
        }
    }

    if (lhi == 0) {
        float bz[3] = {b3[0], b3[1], b3[2]};
#pragma unroll
        for (int g = 0; g < 4; ++g) {
            int v = vg[g] + ln15;
#pragma unroll
            for (int j = 0; j < 3; ++j)
                out[((size_t)b * 3 + j) * N + v] = leaky(acc[g][j] + bz[j]);
        }
    }
}

// ---------------------------------------------------------------------------
extern "C" void kernel_launch(void* const* d_in, const int* in_sizes, int n_in,
                              void* d_out, int out_size, void* d_ws, size_t ws_size,
                              hipStream_t stream) {
    const float* source = (const float*)d_in[0];
    const float* target = (const float*)d_in[1];
    const float* dvf    = (const float*)d_in[2];
    const float* w1 = (const float*)d_in[3];
    const float* b1 = (const float*)d_in[4];
    const float* w2 = (const float*)d_in[5];
    const float* b2 = (const float*)d_in[6];
    const float* w3 = (const float*)d_in[7];
    const float* b3 = (const float*)d_in[8];
    float* out = (float*)d_out;

    // workspace layout (bytes):
    // [0, 113246208)              warped fp32 [2][16][N]  -- later overlaid by X2|X3
    // [113246208, 339738624)      X1 bf16 [2][N][64]
    // then W1f (55296 B), W2f (14336 B), W3f (14336 B)
    char* base = (char*)d_ws;
    float*    warped = (float*)base;
    ushort_t* X2     = (ushort_t*)base;                       // 2*N*16 ushorts
    ushort_t* X3     = (ushort_t*)(base + (size_t)2 * N * 16 * 2);
    ushort_t* X1     = (ushort_t*)(base + (size_t)113246208);
    ushort_t* W1f    = (ushort_t*)(base + (size_t)113246208 + (size_t)2 * N * CP1 * 2);
    ushort_t* W2f    = W1f + NKB1 * 512;
    ushort_t* W3f    = W2f + NKB2 * 512;

    int total = BB * N;                 // 1769472
    int blocks = total / 256;           // 6912

    wprep_kernel<<<(NKB1 * 512 + 2 * NKB2 * 512 + 255) / 256, 256, 0, stream>>>(
        w1, w2, w3, W1f, W2f, W3f);
    warp_kernel<<<blocks, 256, 0, stream>>>(source, dvf, warped, total);
    corr_pack_kernel<<<blocks, 256, 0, stream>>>(source, target, warped, X1, total);
    conv1_mfma<<<blocks, 256, 0, stream>>>(X1, W1f, b1, X2);
    conv2_mfma<<<blocks, 256, 0, stream>>>(X2, W2f, b2, X3);
    conv3_mfma<<<blocks, 256, 0, stream>>>(X3, W3f, b3, out);
}

// Round 5
// 1612.115 us; speedup vs baseline: 2.0682x; 1.6882x over previous
//
#include <hip/hip_runtime.h>

#define LEAK 0.2f

constexpr int BB = 2;
constexpr int C  = 16;
constexpr int D  = 96, H = 96, W = 96;
constexpr int N  = D * H * W;          // 884736
constexpr int HW = H * W;              // 9216
constexpr int DS = 48;                 // dvf spatial

constexpr int CP1  = 64;               // conv1 input channels padded 59->64
constexpr int NKB1 = (27 * CP1) / 32;  // 54 K-blocks for conv1
constexpr int NKB2 = (28 * 16) / 32;   // 14 K-blocks for conv2/conv3 (tap 27 zero-pad)

// conv LDS tile geometry: output tile 4x4x16, halo tile 6x6x18
constexpr int TTZ = 4, TTY = 4, TTX = 16;
constexpr int RRZ = 6, RRY = 6, RRX = 18;
constexpr int ROWS = RRZ * RRY * RRX;  // 648 voxel-rows
constexpr int NTX = W / TTX;           // 6
constexpr int NTY = H / TTY;           // 24
constexpr int NTZ = D / TTZ;           // 24
constexpr int TILES_PER_B = NTX * NTY * NTZ;  // 3456

typedef unsigned short ushort_t;
typedef __attribute__((ext_vector_type(8))) short  short8;
typedef __attribute__((ext_vector_type(8))) unsigned short ushort8;
typedef __attribute__((ext_vector_type(4))) unsigned short ushort4v;
typedef __attribute__((ext_vector_type(4))) float  floatx4;

__device__ __forceinline__ float leaky(float v) { return v > 0.f ? v : LEAK * v; }

__device__ __forceinline__ ushort_t f2bf(float f) {
    union { float f; unsigned u; } v; v.f = f;
    unsigned r = v.u + 0x7FFF + ((v.u >> 16) & 1);
    return (ushort_t)(r >> 16);
}
__device__ __forceinline__ float bf2f(ushort_t h) {
    union { unsigned u; float f; } v; v.u = ((unsigned)h) << 16;
    return v.f;
}

// ---------------------------------------------------------------------------
// Weight repack into MFMA A-fragment order (bf16).
// Wf[kb][lane][e] = W[m = lane&15][k = kb*32 + (lane>>4)*8 + e]
// ---------------------------------------------------------------------------
__global__ void wprep_kernel(const float* __restrict__ w1, const float* __restrict__ w2,
                             const float* __restrict__ w3,
                             ushort_t* __restrict__ W1f, ushort_t* __restrict__ W2f,
                             ushort_t* __restrict__ W3f) {
    int i = blockIdx.x * blockDim.x + threadIdx.x;
    if (i < NKB1 * 512) {
        int kb = i >> 9, rem = i & 511;
        int lane = rem >> 3, e = rem & 7;
        int m = lane & 15;
        int k = kb * 32 + ((lane >> 4) << 3) + e;
        int tap = k >> 6, ci = k & 63;
        float v = (ci < 59) ? w1[((size_t)m * 59 + ci) * 27 + tap] : 0.f;
        W1f[i] = f2bf(v);
        return;
    }
    i -= NKB1 * 512;
    if (i < NKB2 * 512) {
        int kb = i >> 9, rem = i & 511;
        int lane = rem >> 3, e = rem & 7;
        int m = lane & 15;
        int k = kb * 32 + ((lane >> 4) << 3) + e;
        int tap = k >> 4, ci = k & 15;
        float v = (tap < 27) ? w2[((size_t)m * 16 + ci) * 27 + tap] : 0.f;
        W2f[i] = f2bf(v);
        return;
    }
    i -= NKB2 * 512;
    if (i < NKB2 * 512) {
        int kb = i >> 9, rem = i & 511;
        int lane = rem >> 3, e = rem & 7;
        int m = lane & 15;
        int k = kb * 32 + ((lane >> 4) << 3) + e;
        int tap = k >> 4, ci = k & 15;
        float v = (tap < 27 && m < 3) ? w3[((size_t)m * 16 + ci) * 27 + tap] : 0.f;
        W3f[i] = f2bf(v);
    }
}

// ---------------------------------------------------------------------------
// Kernel 1: fused dvf trilinear upsample (align_corners) + warp of source.
// ---------------------------------------------------------------------------
__global__ void warp_kernel(const float* __restrict__ src, const float* __restrict__ dvf,
                            float* __restrict__ warped, int total) {
    int i = blockIdx.x * blockDim.x + threadIdx.x;
    if (i >= total) return;
    int b = i / N; int r = i - b * N;
    int z = r / HW; int rem = r - z * HW; int y = rem / W; int x = rem - y * W;

    const float sc = 47.0f / 95.0f;
    float pz = z * sc, py = y * sc, px = x * sc;
    int z0 = (int)pz, y0 = (int)py, x0 = (int)px;
    int z1 = min(z0 + 1, DS - 1), y1 = min(y0 + 1, DS - 1), x1 = min(x0 + 1, DS - 1);
    float wz = pz - z0, wy = py - y0, wx = px - x0;

    const float* dv = dvf + (size_t)b * 3 * DS * DS * DS;
    float fl[3];
#pragma unroll
    for (int c = 0; c < 3; ++c) {
        const float* p = dv + (size_t)c * DS * DS * DS;
        float c000 = p[(z0 * DS + y0) * DS + x0], c001 = p[(z0 * DS + y0) * DS + x1];
        float c010 = p[(z0 * DS + y1) * DS + x0], c011 = p[(z0 * DS + y1) * DS + x1];
        float c100 = p[(z1 * DS + y0) * DS + x0], c101 = p[(z1 * DS + y0) * DS + x1];
        float c110 = p[(z1 * DS + y1) * DS + x0], c111 = p[(z1 * DS + y1) * DS + x1];
        float a00 = c000 * (1.f - wx) + c001 * wx;
        float a01 = c010 * (1.f - wx) + c011 * wx;
        float a10 = c100 * (1.f - wx) + c101 * wx;
        float a11 = c110 * (1.f - wx) + c111 * wx;
        float b0_ = a00 * (1.f - wy) + a01 * wy;
        float b1_ = a10 * (1.f - wy) + a11 * wy;
        fl[c] = b0_ * (1.f - wz) + b1_ * wz;
    }

    float zz = z + fl[0], yy = y + fl[1], xx = x + fl[2];
    float zf = floorf(zz), yf = floorf(yy), xf = floorf(xx);
    float fz = zz - zf, fy = yy - yf, fx = xx - xf;
    int iz0 = (int)zf, iy0 = (int)yf, ix0 = (int)xf;
    int iz1 = iz0 + 1, iy1 = iy0 + 1, ix1 = ix0 + 1;

    float vz0 = ((unsigned)iz0 < (unsigned)D) ? 1.f : 0.f;
    float vy0 = ((unsigned)iy0 < (unsigned)H) ? 1.f : 0.f;
    float vx0 = ((unsigned)ix0 < (unsigned)W) ? 1.f : 0.f;
    float vz1 = ((unsigned)iz1 < (unsigned)D) ? 1.f : 0.f;
    float vy1 = ((unsigned)iy1 < (unsigned)H) ? 1.f : 0.f;
    float vx1 = ((unsigned)ix1 < (unsigned)W) ? 1.f : 0.f;

    int cz0 = min(max(iz0, 0), D - 1), cy0 = min(max(iy0, 0), H - 1), cx0 = min(max(ix0, 0), W - 1);
    int cz1 = min(max(iz1, 0), D - 1), cy1 = min(max(iy1, 0), H - 1), cx1 = min(max(ix1, 0), W - 1);

    float w000 = (1.f - fz) * (1.f - fy) * (1.f - fx) * vz0 * vy0 * vx0;
    float w001 = (1.f - fz) * (1.f - fy) * fx         * vz0 * vy0 * vx1;
    float w010 = (1.f - fz) * fy * (1.f - fx)         * vz0 * vy1 * vx0;
    float w011 = (1.f - fz) * fy * fx                 * vz0 * vy1 * vx1;
    float w100 = fz * (1.f - fy) * (1.f - fx)         * vz1 * vy0 * vx0;
    float w101 = fz * (1.f - fy) * fx                 * vz1 * vy0 * vx1;
    float w110 = fz * fy * (1.f - fx)                 * vz1 * vy1 * vx0;
    float w111 = fz * fy * fx                         * vz1 * vy1 * vx1;

    int o000 = (cz0 * H + cy0) * W + cx0, o001 = (cz0 * H + cy0) * W + cx1;
    int o010 = (cz0 * H + cy1) * W + cx0, o011 = (cz0 * H + cy1) * W + cx1;
    int o100 = (cz1 * H + cy0) * W + cx0, o101 = (cz1 * H + cy0) * W + cx1;
    int o110 = (cz1 * H + cy1) * W + cx0, o111 = (cz1 * H + cy1) * W + cx1;

    const float* sb = src + (size_t)b * C * N;
    float* wb = warped + (size_t)b * C * N + r;
#pragma unroll 4
    for (int c = 0; c < C; ++c) {
        const float* p = sb + (size_t)c * N;
        float v = p[o000] * w000 + p[o001] * w001 + p[o010] * w010 + p[o011] * w011
                + p[o100] * w100 + p[o101] * w101 + p[o110] * w110 + p[o111] * w111;
        wb[(size_t)c * N] = v;
    }
}

// ---------------------------------------------------------------------------
// Kernel 2: corr (27-shift cost volume, channel-mean, leaky) + pack:
// writes NHWC bf16 row X1[v][64] = [src 0..15 | feat 16..42 | tgt 43..58 | 0]
// ---------------------------------------------------------------------------
__global__ void corr_pack_kernel(const float* __restrict__ src, const float* __restrict__ tgt,
                                 const float* __restrict__ warped, ushort_t* __restrict__ X1,
                                 int total) {
    int nwg = gridDim.x;
    int lb = (blockIdx.x & 7) * (nwg >> 3) + (blockIdx.x >> 3);   // XCD-chunked swizzle
    int i = lb * blockDim.x + threadIdx.x;
    if (i >= total) return;
    int b = i / N; int r = i - b * N;
    int z = r / HW; int rem = r - z * HW; int y = rem / W; int x = rem - y * W;

    int offs[27]; float msk[27];
#pragma unroll
    for (int k = 0; k < 27; ++k) {
        int dz = k / 9 - 1, dy = (k / 3) % 3 - 1, dx = k % 3 - 1;
        int zc = z + dz, yc = y + dy, xc = x + dx;
        bool v = ((unsigned)zc < (unsigned)D) && ((unsigned)yc < (unsigned)H) && ((unsigned)xc < (unsigned)W);
        int zk = min(max(zc, 0), D - 1), yk = min(max(yc, 0), H - 1), xk = min(max(xc, 0), W - 1);
        offs[k] = (zk * H + yk) * W + xk;
        msk[k] = v ? 1.f : 0.f;
    }

    float tv[16], sv[16];
#pragma unroll 4
    for (int c = 0; c < C; ++c) tv[c] = tgt[((size_t)b * C + c) * N + r];
#pragma unroll 4
    for (int c = 0; c < C; ++c) sv[c] = src[((size_t)b * C + c) * N + r];

    float acc[27];
#pragma unroll
    for (int k = 0; k < 27; ++k) acc[k] = 0.f;

    const float* wb = warped + (size_t)b * C * N;
    for (int c = 0; c < C; ++c) {
        float t = tv[c];
        const float* p = wb + (size_t)c * N;
#pragma unroll
        for (int k = 0; k < 27; ++k) acc[k] += t * p[offs[k]];
    }

    ushort8 rowv[8];
#pragma unroll
    for (int c = 0; c < 16; ++c) rowv[c >> 3][c & 7] = f2bf(sv[c]);
#pragma unroll
    for (int k = 0; k < 27; ++k) {
        int p = 16 + k;
        rowv[p >> 3][p & 7] = f2bf(leaky(acc[k] * (1.f / 16.f) * msk[k]));
    }
#pragma unroll
    for (int c = 0; c < 16; ++c) { int p = 43 + c; rowv[p >> 3][p & 7] = f2bf(tv[c]); }
#pragma unroll
    for (int p = 59; p < 64; ++p) rowv[p >> 3][p & 7] = 0;

    ushort8* dst = (ushort8*)(X1 + ((size_t)b * N + r) * CP1);
#pragma unroll
    for (int j = 0; j < 8; ++j) dst[j] = rowv[j];
}

// ---------------------------------------------------------------------------
// Kernel 3: conv1, LDS-tiled MFMA, split-half K staging.
// Per K-half h: stage 32 channels of the 6x6x18 halo (zeros in halo) into
// 41,472 B LDS (3 blocks/CU), then run 27 taps of that half.
// Row = 4 x 16B units; swizzle u' = u ^ ((row>>1)&3) -> 2-way bank alias (free).
// ---------------------------------------------------------------------------
__global__ __launch_bounds__(256) void conv1_lds(const ushort_t* __restrict__ X1,
                                                 const ushort_t* __restrict__ W1f,
                                                 const float* __restrict__ b1,
                                                 ushort_t* __restrict__ X2) {
    __shared__ ushort_t L[ROWS * 32];   // 41472 B
    int nwg = gridDim.x;
    int lb = (blockIdx.x & 7) * (nwg >> 3) + (blockIdx.x >> 3);
    int b = lb / TILES_PER_B; int rem = lb - b * TILES_PER_B;
    int tz = rem / (NTY * NTX); int r2 = rem - tz * (NTY * NTX);
    int ty = r2 / NTX; int tx = r2 - ty * NTX;
    int z0 = tz * TTZ, y0 = ty * TTY, x0 = tx * TTX;
    int tid = threadIdx.x;

    int l = tid & 63, wid = tid >> 6;
    int ln15 = l & 15, lhi = l >> 4;
    int zl_[4], yl_[4];
#pragma unroll
    for (int g = 0; g < 4; ++g) {
        int gi = wid * 4 + g;
        zl_[g] = gi >> 2; yl_[g] = gi & 3;
    }
    floatx4 acc[4] = {};

    for (int h = 0; h < 2; ++h) {
        __syncthreads();   // protect previous half's readers
        for (int t = tid; t < ROWS * 4; t += 256) {
            int row = t >> 2, ut = t & 3;
            int zl = row / (RRY * RRX); int rr = row - zl * (RRY * RRX);
            int yl = rr / RRX; int xl = rr - yl * RRX;
            int gz = z0 + zl - 1, gy = y0 + yl - 1, gx = x0 + xl - 1;
            ushort8 val = {};
            if (((unsigned)gz < (unsigned)D) & ((unsigned)gy < (unsigned)H) & ((unsigned)gx < (unsigned)W)) {
                size_t gv = (size_t)b * N + (gz * HW + gy * W + gx);
                val = *(const ushort8*)(X1 + gv * 64 + (h * 4 + ut) * 8);
            }
            *(ushort8*)(L + row * 32 + ((ut ^ ((row >> 1) & 3)) << 3)) = val;
        }
        __syncthreads();

        for (int tap = 0; tap < 27; ++tap) {
            int kb = tap * 2 + h;
            short8 a = *(const short8*)(W1f + (size_t)(kb * 64 + l) * 8);
            int dz = tap / 9 - 1, dy = (tap / 3) % 3 - 1, dx = tap % 3 - 1;
#pragma unroll
            for (int g = 0; g < 4; ++g) {
                int row = (zl_[g] + 1 + dz) * (RRY * RRX) + (yl_[g] + 1 + dy) * RRX + (1 + dx) + ln15;
                short8 bf = *(const short8*)(L + row * 32 + ((lhi ^ ((row >> 1) & 3)) << 3));
                acc[g] = __builtin_amdgcn_mfma_f32_16x16x32_bf16(a, bf, acc[g], 0, 0, 0);
            }
        }
    }

    int co0 = lhi << 2;
    float bias[4] = {b1[co0], b1[co0 + 1], b1[co0 + 2], b1[co0 + 3]};
#pragma unroll
    for (int g = 0; g < 4; ++g) {
        int gz = z0 + zl_[g], gy = y0 + yl_[g], gx = x0 + ln15;
        size_t v = (size_t)b * N + (gz * HW + gy * W + gx);
        ushort4v o;
#pragma unroll
        for (int j = 0; j < 4; ++j) o[j] = f2bf(leaky(acc[g][j] + bias[j]));
        *(ushort4v*)(X2 + v * 16 + co0) = o;
    }
}

// ---------------------------------------------------------------------------
// Kernel 4: conv2, LDS-tiled MFMA + residual. Rows padded 32->48 B
// (stride-12-dword spreads 16 lanes over all 32 banks, 2-way = free).
// ---------------------------------------------------------------------------
__global__ __launch_bounds__(256) void conv2_lds(const ushort_t* __restrict__ X2,
                                                 const ushort_t* __restrict__ W2f,
                                                 const float* __restrict__ b2,
                                                 ushort_t* __restrict__ X3) {
    __shared__ ushort_t L[ROWS * 24];   // 31104 B
    int nwg = gridDim.x;
    int lb = (blockIdx.x & 7) * (nwg >> 3) + (blockIdx.x >> 3);
    int b = lb / TILES_PER_B; int rem = lb - b * TILES_PER_B;
    int tz = rem / (NTY * NTX); int r2 = rem - tz * (NTY * NTX);
    int ty = r2 / NTX; int tx = r2 - ty * NTX;
    int z0 = tz * TTZ, y0 = ty * TTY, x0 = tx * TTX;
    int tid = threadIdx.x;

    for (int t = tid; t < ROWS * 2; t += 256) {
        int row = t >> 1, u = t & 1;
        int zl = row / (RRY * RRX); int rr = row - zl * (RRY * RRX);
        int yl = rr / RRX; int xl = rr - yl * RRX;
        int gz = z0 + zl - 1, gy = y0 + yl - 1, gx = x0 + xl - 1;
        ushort8 val = {};
        if (((unsigned)gz < (unsigned)D) & ((unsigned)gy < (unsigned)H) & ((unsigned)gx < (unsigned)W)) {
            size_t gv = (size_t)b * N + (gz * HW + gy * W + gx);
            val = *(const ushort8*)(X2 + gv * 16 + u * 8);
        }
        *(ushort8*)(L + row * 24 + u * 8) = val;
    }
    __syncthreads();

    int l = tid & 63, wid = tid >> 6;
    int ln15 = l & 15, lhi = l >> 4;
    int zl_[4], yl_[4];
#pragma unroll
    for (int g = 0; g < 4; ++g) {
        int gi = wid * 4 + g;
        zl_[g] = gi >> 2; yl_[g] = gi & 3;
    }
    floatx4 acc[4] = {};
    int u = lhi & 1;

    for (int kb = 0; kb < NKB2; ++kb) {
        short8 a = *(const short8*)(W2f + (size_t)(kb * 64 + l) * 8);
        int t2 = kb * 2 + (lhi >> 1);
        int tt = (t2 < 27) ? t2 : 13;            // pad tap: A is zero, any valid row
        int dz = tt / 9 - 1, dy = (tt / 3) % 3 - 1, dx = tt % 3 - 1;
#pragma unroll
        for (int g = 0; g < 4; ++g) {
            int row = (zl_[g] + 1 + dz) * (RRY * RRX) + (yl_[g] + 1 + dy) * RRX + (1 + dx) + ln15;
            short8 bf = *(const short8*)(L + row * 24 + u * 8);
            acc[g] = __builtin_amdgcn_mfma_f32_16x16x32_bf16(a, bf, acc[g], 0, 0, 0);
        }
    }

    int co0 = lhi << 2;
    float bias[4] = {b2[co0], b2[co0 + 1], b2[co0 + 2], b2[co0 + 3]};
#pragma unroll
    for (int g = 0; g < 4; ++g) {
        int rowc = (zl_[g] + 1) * (RRY * RRX) + (yl_[g] + 1) * RRX + 1 + ln15;
        ushort4v res = *(const ushort4v*)(L + rowc * 24 + co0);
        int gz = z0 + zl_[g], gy = y0 + yl_[g], gx = x0 + ln15;
        size_t v = (size_t)b * N + (gz * HW + gy * W + gx);
        ushort4v o;
#pragma unroll
        for (int j = 0; j < 4; ++j)
            o[j] = f2bf(bf2f(res[j]) + leaky(acc[g][j] + bias[j]));
        *(ushort4v*)(X3 + v * 16 + co0) = o;
    }
}

// ---------------------------------------------------------------------------
// Kernel 5: conv3, LDS-tiled MFMA -> fp32 planar out (3 channels).
// NOTE: out index uses the WITHIN-BATCH voxel r (round-4 bug: b*N added twice).
// ---------------------------------------------------------------------------
__global__ __launch_bounds__(256) void conv3_lds(const ushort_t* __restrict__ X3,
                                                 const ushort_t* __restrict__ W3f,
                                                 const float* __restrict__ b3,
                                                 float* __restrict__ out) {
    __shared__ ushort_t L[ROWS * 24];
    int nwg = gridDim.x;
    int lb = (blockIdx.x & 7) * (nwg >> 3) + (blockIdx.x >> 3);
    int b = lb / TILES_PER_B; int rem = lb - b * TILES_PER_B;
    int tz = rem / (NTY * NTX); int r2 = rem - tz * (NTY * NTX);
    int ty = r2 / NTX; int tx = r2 - ty * NTX;
    int z0 = tz * TTZ, y0 = ty * TTY, x0 = tx * TTX;
    int tid = threadIdx.x;

    for (int t = tid; t < ROWS * 2; t += 256) {
        int row = t >> 1, u = t & 1;
        int zl = row / (RRY * RRX); int rr = row - zl * (RRY * RRX);
        int yl = rr / RRX; int xl = rr - yl * RRX;
        int gz = z0 + zl - 1, gy = y0 + yl - 1, gx = x0 + xl - 1;
        ushort8 val = {};
        if (((unsigned)gz < (unsigned)D) & ((unsigned)gy < (unsigned)H) & ((unsigned)gx < (unsigned)W)) {
            size_t gv = (size_t)b * N + (gz * HW + gy * W + gx);
            val = *(const ushort8*)(X3 + gv * 16 + u * 8);
        }
        *(ushort8*)(L + row * 24 + u * 8) = val;
    }
    __syncthreads();

    int l = tid & 63, wid = tid >> 6;
    int ln15 = l & 15, lhi = l >> 4;
    int zl_[4], yl_[4];
#pragma unroll
    for (int g = 0; g < 4; ++g) {
        int gi = wid * 4 + g;
        zl_[g] = gi >> 2; yl_[g] = gi & 3;
    }
    floatx4 acc[4] = {};
    int u = lhi & 1;

    for (int kb = 0; kb < NKB2; ++kb) {
        short8 a = *(const short8*)(W3f + (size_t)(kb * 64 + l) * 8);
        int t2 = kb * 2 + (lhi >> 1);
        int tt = (t2 < 27) ? t2 : 13;
        int dz = tt / 9 - 1, dy = (tt / 3) % 3 - 1, dx = tt % 3 - 1;
#pragma unroll
        for (int g = 0; g < 4; ++g) {
            int row = (zl_[g] + 1 + dz) * (RRY * RRX) + (yl_[g] + 1 + dy) * RRX + (1 + dx) + ln15;
            short8 bf = *(const short8*)(L + row * 24 + u * 8);
            acc[g] = __builtin_amdgcn_mfma_f32_16x16x32_bf16(a, bf, acc[g], 0, 0, 0);
        }
    }

    if (lhi == 0) {
        float bz[3] = {b3[0], b3[1], b3[2]};
#pragma unroll
        for (int g = 0; g < 4; ++g) {
            int gz = z0 + zl_[g], gy = y0 + yl_[g], gx = x0 + ln15;
            size_t r = (size_t)(gz * HW + gy * W + gx);   // within-batch voxel
#pragma unroll
            for (int j = 0; j < 3; ++j)
                out[((size_t)b * 3 + j) * N + r] = leaky(acc[g][j] + bz[j]);
        }
    }
}

// ---------------------------------------------------------------------------
extern "C" void kernel_launch(void* const* d_in, const int* in_sizes, int n_in,
                              void* d_out, int out_size, void* d_ws, size_t ws_size,
                              hipStream_t stream) {
    const float* source = (const float*)d_in[0];
    const float* target = (const float*)d_in[1];
    const float* dvf    = (const float*)d_in[2];
    const float* w1 = (const float*)d_in[3];
    const float* b1 = (const float*)d_in[4];
    const float* w2 = (const float*)d_in[5];
    const float* b2 = (const float*)d_in[6];
    const float* w3 = (const float*)d_in[7];
    const float* b3 = (const float*)d_in[8];
    float* out = (float*)d_out;

    // workspace layout (bytes):
    // [0, 113246208)           warped fp32 [2][16][N] -- later overlaid by X2|X3
    // [113246208, 339738624)   X1 bf16 [2][N][64]
    // then W1f / W2f / W3f
    char* base = (char*)d_ws;
    float*    warped = (float*)base;
    ushort_t* X2     = (ushort_t*)base;                       // 2*N*16 ushorts
    ushort_t* X3     = (ushort_t*)(base + (size_t)2 * N * 16 * 2);
    ushort_t* X1     = (ushort_t*)(base + (size_t)113246208);
    ushort_t* W1f    = (ushort_t*)(base + (size_t)113246208 + (size_t)2 * N * CP1 * 2);
    ushort_t* W2f    = W1f + NKB1 * 512;
    ushort_t* W3f    = W2f + NKB2 * 512;

    int total = BB * N;                 // 1769472
    int blocks = total / 256;           // 6912
    int tblocks = BB * TILES_PER_B;     // 6912

    wprep_kernel<<<(NKB1 * 512 + 2 * NKB2 * 512 + 255) / 256, 256, 0, stream>>>(
        w1, w2, w3, W1f, W2f, W3f);
    warp_kernel<<<blocks, 256, 0, stream>>>(source, dvf, warped, total);
    corr_pack_kernel<<<blocks, 256, 0, stream>>>(source, target, warped, X1, total);
    conv1_lds<<<tblocks, 256, 0, stream>>>(X1, W1f, b1, X2);
    conv2_lds<<<tblocks, 256, 0, stream>>>(X2, W2f, b2, X3);
    conv3_lds<<<tblocks, 256, 0, stream>>>(X3, W3f, b3, out);
}

// Round 7
// 987.035 us; speedup vs baseline: 3.3780x; 1.6333x over previous
//
#include <hip/hip_runtime.h>

#define LEAK 0.2f

constexpr int BB = 2;
constexpr int C  = 16;
constexpr int D  = 96, H = 96, W = 96;
constexpr int N  = D * H * W;          // 884736
constexpr int HW = H * W;              // 9216
constexpr int DS = 48;                 // dvf spatial

constexpr int CP1  = 64;               // conv1 input channels padded 59->64
constexpr int NKB1 = (27 * CP1) / 32;  // 54 K-blocks for conv1
constexpr int NKB2 = (28 * 16) / 32;   // 14 K-blocks for conv2/conv3 (tap 27 zero-pad)

// LDS tile geometry (shared by corr + convs): output tile 4x4x16, halo 6x6x18
constexpr int TTZ = 4, TTY = 4, TTX = 16;
constexpr int RRZ = 6, RRY = 6, RRX = 18;
constexpr int ROWS = RRZ * RRY * RRX;  // 648 voxel-rows
constexpr int NTX = W / TTX;           // 6
constexpr int NTY = H / TTY;           // 24
constexpr int NTZ = D / TTZ;           // 24
constexpr int TILES_PER_B = NTX * NTY * NTZ;  // 3456

typedef unsigned short ushort_t;
typedef __attribute__((ext_vector_type(8))) short  short8;
typedef __attribute__((ext_vector_type(8))) unsigned short ushort8;
typedef __attribute__((ext_vector_type(4))) unsigned short ushort4v;
typedef __attribute__((ext_vector_type(4))) float  floatx4;

__device__ __forceinline__ float leaky(float v) { return v > 0.f ? v : LEAK * v; }

__device__ __forceinline__ ushort_t f2bf(float f) {
    union { float f; unsigned u; } v; v.f = f;
    unsigned r = v.u + 0x7FFF + ((v.u >> 16) & 1);
    return (ushort_t)(r >> 16);
}
__device__ __forceinline__ float bf2f(ushort_t h) {
    union { unsigned u; float f; } v; v.u = ((unsigned)h) << 16;
    return v.f;
}

// ---------------------------------------------------------------------------
// Weight repack into MFMA A-fragment order (bf16).
// Wf[kb][lane][e] = W[m = lane&15][k = kb*32 + (lane>>4)*8 + e]
// ---------------------------------------------------------------------------
__global__ void wprep_kernel(const float* __restrict__ w1, const float* __restrict__ w2,
                             const float* __restrict__ w3,
                             ushort_t* __restrict__ W1f, ushort_t* __restrict__ W2f,
                             ushort_t* __restrict__ W3f) {
    int i = blockIdx.x * blockDim.x + threadIdx.x;
    if (i < NKB1 * 512) {
        int kb = i >> 9, rem = i & 511;
        int lane = rem >> 3, e = rem & 7;
        int m = lane & 15;
        int k = kb * 32 + ((lane >> 4) << 3) + e;
        int tap = k >> 6, ci = k & 63;
        float v = (ci < 59) ? w1[((size_t)m * 59 + ci) * 27 + tap] : 0.f;
        W1f[i] = f2bf(v);
        return;
    }
    i -= NKB1 * 512;
    if (i < NKB2 * 512) {
        int kb = i >> 9, rem = i & 511;
        int lane = rem >> 3, e = rem & 7;
        int m = lane & 15;
        int k = kb * 32 + ((lane >> 4) << 3) + e;
        int tap = k >> 4, ci = k & 15;
        float v = (tap < 27) ? w2[((size_t)m * 16 + ci) * 27 + tap] : 0.f;
        W2f[i] = f2bf(v);
        return;
    }
    i -= NKB2 * 512;
    if (i < NKB2 * 512) {
        int kb = i >> 9, rem = i & 511;
        int lane = rem >> 3, e = rem & 7;
        int m = lane & 15;
        int k = kb * 32 + ((lane >> 4) << 3) + e;
        int tap = k >> 4, ci = k & 15;
        float v = (tap < 27 && m < 3) ? w3[((size_t)m * 16 + ci) * 27 + tap] : 0.f;
        W3f[i] = f2bf(v);
    }
}

// ---------------------------------------------------------------------------
// Kernel 1: fused dvf trilinear upsample (align_corners) + warp of source.
// ---------------------------------------------------------------------------
__global__ void warp_kernel(const float* __restrict__ src, const float* __restrict__ dvf,
                            float* __restrict__ warped, int total) {
    int i = blockIdx.x * blockDim.x + threadIdx.x;
    if (i >= total) return;
    int b = i / N; int r = i - b * N;
    int z = r / HW; int rem = r - z * HW; int y = rem / W; int x = rem - y * W;

    const float sc = 47.0f / 95.0f;
    float pz = z * sc, py = y * sc, px = x * sc;
    int z0 = (int)pz, y0 = (int)py, x0 = (int)px;
    int z1 = min(z0 + 1, DS - 1), y1 = min(y0 + 1, DS - 1), x1 = min(x0 + 1, DS - 1);
    float wz = pz - z0, wy = py - y0, wx = px - x0;

    const float* dv = dvf + (size_t)b * 3 * DS * DS * DS;
    float fl[3];
#pragma unroll
    for (int c = 0; c < 3; ++c) {
        const float* p = dv + (size_t)c * DS * DS * DS;
        float c000 = p[(z0 * DS + y0) * DS + x0], c001 = p[(z0 * DS + y0) * DS + x1];
        float c010 = p[(z0 * DS + y1) * DS + x0], c011 = p[(z0 * DS + y1) * DS + x1];
        float c100 = p[(z1 * DS + y0) * DS + x0], c101 = p[(z1 * DS + y0) * DS + x1];
        float c110 = p[(z1 * DS + y1) * DS + x0], c111 = p[(z1 * DS + y1) * DS + x1];
        float a00 = c000 * (1.f - wx) + c001 * wx;
        float a01 = c010 * (1.f - wx) + c011 * wx;
        float a10 = c100 * (1.f - wx) + c101 * wx;
        float a11 = c110 * (1.f - wx) + c111 * wx;
        float b0_ = a00 * (1.f - wy) + a01 * wy;
        float b1_ = a10 * (1.f - wy) + a11 * wy;
        fl[c] = b0_ * (1.f - wz) + b1_ * wz;
    }

    float zz = z + fl[0], yy = y + fl[1], xx = x + fl[2];
    float zf = floorf(zz), yf = floorf(yy), xf = floorf(xx);
    float fz = zz - zf, fy = yy - yf, fx = xx - xf;
    int iz0 = (int)zf, iy0 = (int)yf, ix0 = (int)xf;
    int iz1 = iz0 + 1, iy1 = iy0 + 1, ix1 = ix0 + 1;

    float vz0 = ((unsigned)iz0 < (unsigned)D) ? 1.f : 0.f;
    float vy0 = ((unsigned)iy0 < (unsigned)H) ? 1.f : 0.f;
    float vx0 = ((unsigned)ix0 < (unsigned)W) ? 1.f : 0.f;
    float vz1 = ((unsigned)iz1 < (unsigned)D) ? 1.f : 0.f;
    float vy1 = ((unsigned)iy1 < (unsigned)H) ? 1.f : 0.f;
    float vx1 = ((unsigned)ix1 < (unsigned)W) ? 1.f : 0.f;

    int cz0 = min(max(iz0, 0), D - 1), cy0 = min(max(iy0, 0), H - 1), cx0 = min(max(ix0, 0), W - 1);
    int cz1 = min(max(iz1, 0), D - 1), cy1 = min(max(iy1, 0), H - 1), cx1 = min(max(ix1, 0), W - 1);

    float w000 = (1.f - fz) * (1.f - fy) * (1.f - fx) * vz0 * vy0 * vx0;
    float w001 = (1.f - fz) * (1.f - fy) * fx         * vz0 * vy0 * vx1;
    float w010 = (1.f - fz) * fy * (1.f - fx)         * vz0 * vy1 * vx0;
    float w011 = (1.f - fz) * fy * fx                 * vz0 * vy1 * vx1;
    float w100 = fz * (1.f - fy) * (1.f - fx)         * vz1 * vy0 * vx0;
    float w101 = fz * (1.f - fy) * fx                 * vz1 * vy0 * vx1;
    float w110 = fz * fy * (1.f - fx)                 * vz1 * vy1 * vx0;
    float w111 = fz * fy * fx                         * vz1 * vy1 * vx1;

    int o000 = (cz0 * H + cy0) * W + cx0, o001 = (cz0 * H + cy0) * W + cx1;
    int o010 = (cz0 * H + cy1) * W + cx0, o011 = (cz0 * H + cy1) * W + cx1;
    int o100 = (cz1 * H + cy0) * W + cx0, o101 = (cz1 * H + cy0) * W + cx1;
    int o110 = (cz1 * H + cy1) * W + cx0, o111 = (cz1 * H + cy1) * W + cx1;

    const float* sb = src + (size_t)b * C * N;
    float* wb = warped + (size_t)b * C * N + r;
#pragma unroll 4
    for (int c = 0; c < C; ++c) {
        const float* p = sb + (size_t)c * N;
        float v = p[o000] * w000 + p[o001] * w001 + p[o010] * w010 + p[o011] * w011
                + p[o100] * w100 + p[o101] * w101 + p[o110] * w110 + p[o111] * w111;
        wb[(size_t)c * N] = v;
    }
}

// ---------------------------------------------------------------------------
// Kernel 2: corr + pack, LDS-tiled.
// Stage warped halo (6x6x18 x 16ch fp32, zeros in halo = exact zero-pad
// semantics) with float4-unit swizzle u' = u ^ ((row>>1)&3).
// Compute acc[27] from LDS; pack NHWC row; coalesce X1 writes via reused LDS.
// ---------------------------------------------------------------------------
__global__ __launch_bounds__(256) void corr_pack_lds(const float* __restrict__ src,
                                                     const float* __restrict__ tgt,
                                                     const float* __restrict__ warped,
                                                     ushort_t* __restrict__ X1) {
    __shared__ float Lw[ROWS * 16];   // 41472 B; reused as 32KB pack buffer
    int nwg = gridDim.x;
    int lb = (blockIdx.x & 7) * (nwg >> 3) + (blockIdx.x >> 3);
    int b = lb / TILES_PER_B; int rem = lb - b * TILES_PER_B;
    int tz = rem / (NTY * NTX); int r2 = rem - tz * (NTY * NTX);
    int ty = r2 / NTX; int tx = r2 - ty * NTX;
    int z0 = tz * TTZ, y0 = ty * TTY, x0 = tx * TTX;
    int tid = threadIdx.x;

    const float* wb = warped + (size_t)b * C * N;

    // ---- stage warped halo: items (row, u), u = float4 unit (4 channels)
    for (int t = tid; t < ROWS * 4; t += 256) {
        int row = t >> 2, u = t & 3;
        int zl = row / (RRY * RRX); int rr = row - zl * (RRY * RRX);
        int yl = rr / RRX; int xl = rr - yl * RRX;
        int gz = z0 + zl - 1, gy = y0 + yl - 1, gx = x0 + xl - 1;
        floatx4 v = {};
        if (((unsigned)gz < (unsigned)D) & ((unsigned)gy < (unsigned)H) & ((unsigned)gx < (unsigned)W)) {
            int o = gz * HW + gy * W + gx;
            v[0] = wb[(size_t)(u * 4 + 0) * N + o];
            v[1] = wb[(size_t)(u * 4 + 1) * N + o];
            v[2] = wb[(size_t)(u * 4 + 2) * N + o];
            v[3] = wb[(size_t)(u * 4 + 3) * N + o];
        }
        *(floatx4*)(Lw + row * 16 + ((u ^ ((row >> 1) & 3)) << 2)) = v;
    }
    __syncthreads();

    // ---- per-thread voxel
    int xl = tid & 15, yl = (tid >> 4) & 3, zl = tid >> 6;
    int r = (z0 + zl) * HW + (y0 + yl) * W + (x0 + xl);

    float sv[16], tv[16];
#pragma unroll 4
    for (int c = 0; c < C; ++c) sv[c] = src[((size_t)b * C + c) * N + r];
#pragma unroll 4
    for (int c = 0; c < C; ++c) tv[c] = tgt[((size_t)b * C + c) * N + r];

    float acc[27];
#pragma unroll
    for (int k = 0; k < 27; ++k) acc[k] = 0.f;

#pragma unroll 3
    for (int k = 0; k < 27; ++k) {
        int dz = k / 9 - 1, dy = (k / 3) % 3 - 1, dx = k % 3 - 1;
        int row = (zl + 1 + dz) * (RRY * RRX) + (yl + 1 + dy) * RRX + (1 + dx) + xl;
        int sw = (row >> 1) & 3;
        float a = 0.f;
#pragma unroll
        for (int u = 0; u < 4; ++u) {
            floatx4 p = *(const floatx4*)(Lw + row * 16 + ((u ^ sw) << 2));
            a += tv[u * 4 + 0] * p[0] + tv[u * 4 + 1] * p[1]
               + tv[u * 4 + 2] * p[2] + tv[u * 4 + 3] * p[3];
        }
        acc[k] = a;
    }

    // ---- pack NHWC row in registers
    ushort8 rowv[8];
#pragma unroll
    for (int c = 0; c < 16; ++c) rowv[c >> 3][c & 7] = f2bf(sv[c]);
#pragma unroll
    for (int k = 0; k < 27; ++k) {
        int p = 16 + k;
        rowv[p >> 3][p & 7] = f2bf(leaky(acc[k] * (1.f / 16.f)));
    }
#pragma unroll
    for (int c = 0; c < 16; ++c) { int p = 43 + c; rowv[p >> 3][p & 7] = f2bf(tv[c]); }
#pragma unroll
    for (int p = 59; p < 64; ++p) rowv[p >> 3][p & 7] = 0;

    __syncthreads();   // all LDS reads of Lw done
    ushort_t* Lp = (ushort_t*)Lw;      // 256 rows x 128 B = 32768 B
#pragma unroll
    for (int j = 0; j < 8; ++j)
        *(ushort8*)(Lp + tid * 64 + ((j ^ (tid & 7)) << 3)) = rowv[j];
    __syncthreads();

    // ---- cooperative coalesced write: 16 segments (z,y rows) x 2 KB
#pragma unroll
    for (int it = 0; it < 8; ++it) {
        int gidx = it * 256 + tid;
        int seg = gidx >> 7;           // 0..15
        int within = gidx & 127;
        int vx = within >> 3;          // voxel in segment
        int j  = within & 7;           // 16B unit in row
        int tsrc = seg * 16 + vx;
        ushort8 val = *(const ushort8*)(Lp + tsrc * 64 + ((j ^ (tsrc & 7)) << 3));
        int sz = seg >> 2, sy = seg & 3;
        size_t gbase = ((size_t)b * N + (size_t)((z0 + sz) * HW + (y0 + sy) * W + x0)) * 64;
        *(ushort8*)(X1 + gbase + (size_t)vx * 64 + j * 8) = val;
    }
}

// ---------------------------------------------------------------------------
// Kernel 3: conv1, LDS-tiled MFMA, split-half K staging.
// ---------------------------------------------------------------------------
__global__ __launch_bounds__(256) void conv1_lds(const ushort_t* __restrict__ X1,
                                                 const ushort_t* __restrict__ W1f,
                                                 const float* __restrict__ b1,
                                                 ushort_t* __restrict__ X2) {
    __shared__ ushort_t L[ROWS * 32];   // 41472 B
    int nwg = gridDim.x;
    int lb = (blockIdx.x & 7) * (nwg >> 3) + (blockIdx.x >> 3);
    int b = lb / TILES_PER_B; int rem = lb - b * TILES_PER_B;
    int tz = rem / (NTY * NTX); int r2 = rem - tz * (NTY * NTX);
    int ty = r2 / NTX; int tx = r2 - ty * NTX;
    int z0 = tz * TTZ, y0 = ty * TTY, x0 = tx * TTX;
    int tid = threadIdx.x;

    int l = tid & 63, wid = tid >> 6;
    int ln15 = l & 15, lhi = l >> 4;
    int zl_[4], yl_[4];
#pragma unroll
    for (int g = 0; g < 4; ++g) {
        int gi = wid * 4 + g;
        zl_[g] = gi >> 2; yl_[g] = gi & 3;
    }
    floatx4 acc[4] = {};

    for (int h = 0; h < 2; ++h) {
        __syncthreads();
        for (int t = tid; t < ROWS * 4; t += 256) {
            int row = t >> 2, ut = t & 3;
            int zl = row / (RRY * RRX); int rr = row - zl * (RRY * RRX);
            int yl = rr / RRX; int xl = rr - yl * RRX;
            int gz = z0 + zl - 1, gy = y0 + yl - 1, gx = x0 + xl - 1;
            ushort8 val = {};
            if (((unsigned)gz < (unsigned)D) & ((unsigned)gy < (unsigned)H) & ((unsigned)gx < (unsigned)W)) {
                size_t gv = (size_t)b * N + (gz * HW + gy * W + gx);
                val = *(const ushort8*)(X1 + gv * 64 + (h * 4 + ut) * 8);
            }
            *(ushort8*)(L + row * 32 + ((ut ^ ((row >> 1) & 3)) << 3)) = val;
        }
        __syncthreads();

        for (int tap = 0; tap < 27; ++tap) {
            int kb = tap * 2 + h;
            short8 a = *(const short8*)(W1f + (size_t)(kb * 64 + l) * 8);
            int dz = tap / 9 - 1, dy = (tap / 3) % 3 - 1, dx = tap % 3 - 1;
#pragma unroll
            for (int g = 0; g < 4; ++g) {
                int row = (zl_[g] + 1 + dz) * (RRY * RRX) + (yl_[g] + 1 + dy) * RRX + (1 + dx) + ln15;
                short8 bf = *(const short8*)(L + row * 32 + ((lhi ^ ((row >> 1) & 3)) << 3));
                acc[g] = __builtin_amdgcn_mfma_f32_16x16x32_bf16(a, bf, acc[g], 0, 0, 0);
            }
        }
    }

    int co0 = lhi << 2;
    float bias[4] = {b1[co0], b1[co0 + 1], b1[co0 + 2], b1[co0 + 3]};
#pragma unroll
    for (int g = 0; g < 4; ++g) {
        int gz = z0 + zl_[g], gy = y0 + yl_[g], gx = x0 + ln15;
        size_t v = (size_t)b * N + (gz * HW + gy * W + gx);
        ushort4v o;
#pragma unroll
        for (int j = 0; j < 4; ++j) o[j] = f2bf(leaky(acc[g][j] + bias[j]));
        *(ushort4v*)(X2 + v * 16 + co0) = o;
    }
}

// ---------------------------------------------------------------------------
// Kernel 4: conv2, LDS-tiled MFMA + residual. Rows padded 32->48 B.
// ---------------------------------------------------------------------------
__global__ __launch_bounds__(256) void conv2_lds(const ushort_t* __restrict__ X2,
                                                 const ushort_t* __restrict__ W2f,
                                                 const float* __restrict__ b2,
                                                 ushort_t* __restrict__ X3) {
    __shared__ ushort_t L[ROWS * 24];   // 31104 B
    int nwg = gridDim.x;
    int lb = (blockIdx.x & 7) * (nwg >> 3) + (blockIdx.x >> 3);
    int b = lb / TILES_PER_B; int rem = lb - b * TILES_PER_B;
    int tz = rem / (NTY * NTX); int r2 = rem - tz * (NTY * NTX);
    int ty = r2 / NTX; int tx = r2 - ty * NTX;
    int z0 = tz * TTZ, y0 = ty * TTY, x0 = tx * TTX;
    int tid = threadIdx.x;

    for (int t = tid; t < ROWS * 2; t += 256) {
        int row = t >> 1, u = t & 1;
        int zl = row / (RRY * RRX); int rr = row - zl * (RRY * RRX);
        int yl = rr / RRX; int xl = rr - yl * RRX;
        int gz = z0 + zl - 1, gy = y0 + yl - 1, gx = x0 + xl - 1;
        ushort8 val = {};
        if (((unsigned)gz < (unsigned)D) & ((unsigned)gy < (unsigned)H) & ((unsigned)gx < (unsigned)W)) {
            size_t gv = (size_t)b * N + (gz * HW + gy * W + gx);
            val = *(const ushort8*)(X2 + gv * 16 + u * 8);
        }
        *(ushort8*)(L + row * 24 + u * 8) = val;
    }
    __syncthreads();

    int l = tid & 63, wid = tid >> 6;
    int ln15 = l & 15, lhi = l >> 4;
    int zl_[4], yl_[4];
#pragma unroll
    for (int g = 0; g < 4; ++g) {
        int gi = wid * 4 + g;
        zl_[g] = gi >> 2; yl_[g] = gi & 3;
    }
    floatx4 acc[4] = {};
    int u = lhi & 1;

    for (int kb = 0; kb < NKB2; ++kb) {
        short8 a = *(const short8*)(W2f + (size_t)(kb * 64 + l) * 8);
        int t2 = kb * 2 + (lhi >> 1);
        int tt = (t2 < 27) ? t2 : 13;
        int dz = tt / 9 - 1, dy = (tt / 3) % 3 - 1, dx = tt % 3 - 1;
#pragma unroll
        for (int g = 0; g < 4; ++g) {
            int row = (zl_[g] + 1 + dz) * (RRY * RRX) + (yl_[g] + 1 + dy) * RRX + (1 + dx) + ln15;
            short8 bf = *(const short8*)(L + row * 24 + u * 8);
            acc[g] = __builtin_amdgcn_mfma_f32_16x16x32_bf16(a, bf, acc[g], 0, 0, 0);
        }
    }

    int co0 = lhi << 2;
    float bias[4] = {b2[co0], b2[co0 + 1], b2[co0 + 2], b2[co0 + 3]};
#pragma unroll
    for (int g = 0; g < 4; ++g) {
        int rowc = (zl_[g] + 1) * (RRY * RRX) + (yl_[g] + 1) * RRX + 1 + ln15;
        ushort4v res = *(const ushort4v*)(L + rowc * 24 + co0);
        int gz = z0 + zl_[g], gy = y0 + yl_[g], gx = x0 + ln15;
        size_t v = (size_t)b * N + (gz * HW + gy * W + gx);
        ushort4v o;
#pragma unroll
        for (int j = 0; j < 4; ++j)
            o[j] = f2bf(bf2f(res[j]) + leaky(acc[g][j] + bias[j]));
        *(ushort4v*)(X3 + v * 16 + co0) = o;
    }
}

// ---------------------------------------------------------------------------
// Kernel 5: conv3, LDS-tiled MFMA -> fp32 planar out (3 channels).
// ---------------------------------------------------------------------------
__global__ __launch_bounds__(256) void conv3_lds(const ushort_t* __restrict__ X3,
                                                 const ushort_t* __restrict__ W3f,
                                                 const float* __restrict__ b3,
                                                 float* __restrict__ out) {
    __shared__ ushort_t L[ROWS * 24];
    int nwg = gridDim.x;
    int lb = (blockIdx.x & 7) * (nwg >> 3) + (blockIdx.x >> 3);
    int b = lb / TILES_PER_B; int rem = lb - b * TILES_PER_B;
    int tz = rem / (NTY * NTX); int r2 = rem - tz * (NTY * NTX);
    int ty = r2 / NTX; int tx = r2 - ty * NTX;
    int z0 = tz * TTZ, y0 = ty * TTY, x0 = tx * TTX;
    int tid = threadIdx.x;

    for (int t = tid; t < ROWS * 2; t += 256) {
        int row = t >> 1, u = t & 1;
        int zl = row / (RRY * RRX); int rr = row - zl * (RRY * RRX);
        int yl = rr / RRX; int xl = rr - yl * RRX;
        int gz = z0 + zl - 1, gy = y0 + yl - 1, gx = x0 + xl - 1;
        ushort8 val = {};
        if (((unsigned)gz < (unsigned)D) & ((unsigned)gy < (unsigned)H) & ((unsigned)gx < (unsigned)W)) {
            size_t gv = (size_t)b * N + (gz * HW + gy * W + gx);
            val = *(const ushort8*)(X3 + gv * 16 + u * 8);
        }
        *(ushort8*)(L + row * 24 + u * 8) = val;
    }
    __syncthreads();

    int l = tid & 63, wid = tid >> 6;
    int ln15 = l & 15, lhi = l >> 4;
    int zl_[4], yl_[4];
#pragma unroll
    for (int g = 0; g < 4; ++g) {
        int gi = wid * 4 + g;
        zl_[g] = gi >> 2; yl_[g] = gi & 3;
    }
    floatx4 acc[4] = {};
    int u = lhi & 1;

    for (int kb = 0; kb < NKB2; ++kb) {
        short8 a = *(const short8*)(W3f + (size_t)(kb * 64 + l) * 8);
        int t2 = kb * 2 + (lhi >> 1);
        int tt = (t2 < 27) ? t2 : 13;
        int dz = tt / 9 - 1, dy = (tt / 3) % 3 - 1, dx = tt % 3 - 1;
#pragma unroll
        for (int g = 0; g < 4; ++g) {
            int row = (zl_[g] + 1 + dz) * (RRY * RRX) + (yl_[g] + 1 + dy) * RRX + (1 + dx) + ln15;
            short8 bf = *(const short8*)(L + row * 24 + u * 8);
            acc[g] = __builtin_amdgcn_mfma_f32_16x16x32_bf16(a, bf, acc[g], 0, 0, 0);
        }
    }

    if (lhi == 0) {
        float bz[3] = {b3[0], b3[1], b3[2]};
#pragma unroll
        for (int g = 0; g < 4; ++g) {
            int gz = z0 + zl_[g], gy = y0 + yl_[g], gx = x0 + ln15;
            size_t r = (size_t)(gz * HW + gy * W + gx);   // within-batch voxel
#pragma unroll
            for (int j = 0; j < 3; ++j)
                out[((size_t)b * 3 + j) * N + r] = leaky(acc[g][j] + bz[j]);
        }
    }
}

// ---------------------------------------------------------------------------
extern "C" void kernel_launch(void* const* d_in, const int* in_sizes, int n_in,
                              void* d_out, int out_size, void* d_ws, size_t ws_size,
                              hipStream_t stream) {
    const float* source = (const float*)d_in[0];
    const float* target = (const float*)d_in[1];
    const float* dvf    = (const float*)d_in[2];
    const float* w1 = (const float*)d_in[3];
    const float* b1 = (const float*)d_in[4];
    const float* w2 = (const float*)d_in[5];
    const float* b2 = (const float*)d_in[6];
    const float* w3 = (const float*)d_in[7];
    const float* b3 = (const float*)d_in[8];
    float* out = (float*)d_out;

    char* base = (char*)d_ws;
    float*    warped = (float*)base;
    ushort_t* X2     = (ushort_t*)base;                       // 2*N*16 ushorts
    ushort_t* X3     = (ushort_t*)(base + (size_t)2 * N * 16 * 2);
    ushort_t* X1     = (ushort_t*)(base + (size_t)113246208);
    ushort_t* W1f    = (ushort_t*)(base + (size_t)113246208 + (size_t)2 * N * CP1 * 2);
    ushort_t* W2f    = W1f + NKB1 * 512;
    ushort_t* W3f    = W2f + NKB2 * 512;

    int total = BB * N;                 // 1769472
    int blocks = total / 256;           // 6912
    int tblocks = BB * TILES_PER_B;     // 6912

    wprep_kernel<<<(NKB1 * 512 + 2 * NKB2 * 512 + 255) / 256, 256, 0, stream>>>(
        w1, w2, w3, W1f, W2f, W3f);
    warp_kernel<<<blocks, 256, 0, stream>>>(source, dvf, warped, total);
    corr_pack_lds<<<tblocks, 256, 0, stream>>>(source, target, warped, X1);
    conv1_lds<<<tblocks, 256, 0, stream>>>(X1, W1f, b1, X2);
    conv2_lds<<<tblocks, 256, 0, stream>>>(X2, W2f, b2, X3);
    conv3_lds<<<tblocks, 256, 0, stream>>>(X3, W3f, b3, out);
}